// Round 6
// baseline (130.600 us; speedup 1.0000x reference)
//
#include <hip/hip_runtime.h>

#define BATCH 16
#define HH 512
#define WW 512
#define PLANE (HH*WW)

// Compiler memory-order fences for wave-synchronous LDS exchange.
// HW processes a wave's DS ops in order; these stop the compiler from
// reordering ds_write/ds_read across the cross-lane dependency.
#define LDS_WAIT()   asm volatile("s_waitcnt lgkmcnt(0)" ::: "memory")
#define WAVE_FENCE() asm volatile("" ::: "memory")

// bf16 helpers: gp word = guide in low 16 bits, p in high 16 bits
__device__ __forceinline__ float bf_lo(unsigned u) {
    union { unsigned u; float f; } c; c.u = u << 16; return c.f;
}
__device__ __forceinline__ float bf_hi(unsigned u) {
    union { unsigned u; float f; } c; c.u = u & 0xFFFF0000u; return c.f;
}
__device__ __forceinline__ unsigned f2bf(float f) {   // RTNE, returns low-16 bf16
    union { float f; unsigned u; } c; c.f = f;
    return (c.u + 0x7FFFu + ((c.u >> 16) & 1u)) >> 16;
}

// ---------------- K1: guide (channel mean) + 15x15 replicate min-pool -> packed bf16 (g,p) ----------------
#define T1 64
#define HALO 7
#define LW (T1 + 2*HALO)   // 78

__global__ __launch_bounds__(256) void k1_guide_minpool(
    const float* __restrict__ smoky, unsigned* __restrict__ gp)
{
    __shared__ float dcp[LW*LW];          // per-pixel channel min, with replicate halo
    __shared__ float vmn[T1*LW];          // vertical 15-min
    __shared__ unsigned short gsh[T1*T1]; // guide (bf16) for interior
    int nwg = gridDim.x;             // 1024, divisible by 8
    int wg = (blockIdx.x & 7) * (nwg >> 3) + (blockIdx.x >> 3);  // XCD-chunked swizzle
    int img  = wg >> 6;              // 64 tiles per image
    int tile = wg & 63;
    int y0 = (tile >> 3) * T1;
    int x0 = (tile & 7) * T1;
    int t = threadIdx.x;
    const float* s0 = smoky + (size_t)img * 3 * PLANE;
    unsigned* gpl = gp + (size_t)img * PLANE;

    for (int i = t; i < LW*LW; i += 256) {
        int ly = i / LW, lx = i - ly * LW;
        int iy = y0 - HALO + ly, ix = x0 - HALO + lx;
        int cy = min(max(iy, 0), HH-1);
        int cx = min(max(ix, 0), WW-1);
        const float* bp = s0 + cy * WW + cx;
        float c0 = bp[0], c1 = bp[PLANE], c2 = bp[2*PLANE];
        dcp[i] = fminf(fminf(c0, c1), c2);
        if (ly >= HALO && ly < HALO+T1 && lx >= HALO && lx < HALO+T1)
            gsh[(ly-HALO)*T1 + (lx-HALO)] = (unsigned short)f2bf((c0 + c1 + c2) * (1.0f/3.0f));
    }
    __syncthreads();
    for (int i = t; i < T1*LW; i += 256) {
        int r = i / LW, c = i - r * LW;
        float m = dcp[r*LW + c];
        #pragma unroll
        for (int d = 1; d < 15; ++d) m = fminf(m, dcp[(r+d)*LW + c]);
        vmn[i] = m;
    }
    __syncthreads();
    for (int i = t; i < T1*T1; i += 256) {
        int r = i >> 6, c = i & 63;
        float m = vmn[r*LW + c];
        #pragma unroll
        for (int d = 1; d < 15; ++d) m = fminf(m, vmn[r*LW + c + d]);
        gpl[(y0+r)*WW + x0 + c] = (unsigned)gsh[r*T1+c] | (f2bf(m) << 16);
    }
}

// ---------------- K23: fused cascaded box filters, wave-autonomous ----------------
// Wave owns 64 output cols x 32 output rows. Slides down: col-sums of (I,II,p,Ip)
// in registers -> a,b into 16-row LDS ring -> col-sums of (a,b) -> emit row t-7.
#define SEG 32

__global__ __launch_bounds__(64) void k23(
    const unsigned* __restrict__ gp, const float* __restrict__ smoky,
    const float* __restrict__ rho, float* __restrict__ out)
{
    __shared__ float2 eGI[96];        // (sumI, sumII) exchange, slot j = col c0-14+j
    __shared__ float2 ePQ[96];        // (sumP, sumIp)
    __shared__ float2 ring[16][80];   // (a,b) rows ring, col k = c0-7+k
    __shared__ float2 eAB[80];        // (sumA, sumB) exchange

    int nwg = gridDim.x;              // 2048
    int wg = (blockIdx.x & 7) * (nwg >> 3) + (blockIdx.x >> 3);
    int l = threadIdx.x;              // 0..63, one wave per block
    int img = wg >> 7;                // 128 waves per image
    int cg  = (wg >> 4) & 7;
    int seg = wg & 15;
    int y0 = seg * SEG;
    int c0 = cg * 64;

    const unsigned* gpP = gp + (size_t)img * PLANE;
    const float* sPl = smoky + (size_t)img * 3 * PLANE;
    const float* rPl = rho   + (size_t)img * 3 * PLANE;
    float* oPl = out + (size_t)img * 3 * PLANE;

    int colA = c0 - 14 + l;           // slot l        (always < 512)
    int colB = c0 + 50 + l;           // slot 64+l, lanes 0..27
    bool vA = (colA >= 0);
    bool vB = (l < 28) && (colB < WW);

    auto loadgp = [&](int y, unsigned& a, unsigned& b) {
        a = 0u; b = 0u;
        if ((unsigned)y < (unsigned)HH) {
            const unsigned* r = gpP + (size_t)y * WW;
            if (vA) a = r[colA];
            if (vB) b = r[colB];
        }
    };

    float sI0=0,sII0=0,sP0=0,sIp0=0, sI1=0,sII1=0,sP1=0,sIp1=0;
    float sA0=0,sB0=0,sA1=0,sB1=0;

    // col-sum warm-up: rows [y0-15, y0-1]  (window(t0-1) for t0 = y0-7)
    for (int r = y0-15; r <= y0-1; ++r) {
        unsigned a,b; loadgp(r,a,b);
        float g0=bf_lo(a), p0=bf_hi(a), g1=bf_lo(b), p1=bf_hi(b);
        sI0+=g0; sII0+=g0*g0; sP0+=p0; sIp0+=g0*p0;
        sI1+=g1; sII1+=g1*g1; sP1+=p1; sIp1+=g1*p1;
    }

    unsigned adA, adB, sbA, sbB;
    loadgp(y0,    adA, adB);          // add row for t0:  t0+7 = y0
    loadgp(y0-15, sbA, sbB);          // sub row for t0:  t0-8 = y0-15
    unsigned emG=0; float emS0=0,emS1=0,emS2=0,emR0=0,emR1=0,emR2=0;

    const float inv225 = 1.0f/225.0f;
    const float inv11  = 1.0f/1.1f;

    // t = a,b production row; emit row = t-7
    for (int t = y0-7; t <= y0+38; ++t) {
        // 1. slide (I,II,p,Ip) col-sums: +row(t+7) -row(t-8)
        {
            float gA0=bf_lo(adA), pA0=bf_hi(adA), gA1=bf_lo(adB), pA1=bf_hi(adB);
            float gS0=bf_lo(sbA), pS0=bf_hi(sbA), gS1=bf_lo(sbB), pS1=bf_hi(sbB);
            sI0 += gA0-gS0; sII0 += gA0*gA0-gS0*gS0; sP0 += pA0-pS0; sIp0 += gA0*pA0-gS0*pS0;
            sI1 += gA1-gS1; sII1 += gA1*gA1-gS1*gS1; sP1 += pA1-pS1; sIp1 += gA1*pA1-gS1*pS1;
        }
        // 2. move emit operands to locals before prefetch overwrites them
        bool emitNow = (t >= y0+7);
        float ge=0, s0=0,s1=0,s2=0, r0=0,r1=0,r2=0;
        if (emitNow) { ge=bf_lo(emG); s0=emS0; s1=emS1; s2=emS2; r0=emR0; r1=emR1; r2=emR2; }
        // 3. prefetch next iteration's operands
        loadgp(t+8, adA, adB);
        loadgp(t-7, sbA, sbB);
        if (t >= y0+6 && t <= y0+37) {
            int e = t-6;
            size_t off = (size_t)e*WW + c0 + l;
            emG  = gpP[off];
            emS0 = sPl[off]; emS1 = sPl[off+PLANE]; emS2 = sPl[off+2*PLANE];
            emR0 = rPl[off]; emR1 = rPl[off+PLANE]; emR2 = rPl[off+2*PLANE];
        }
        // 4. produce a,b at row t (zero-pad rows outside image are never produced)
        if ((unsigned)t < (unsigned)HH) {
            eGI[l] = make_float2(sI0, sII0);
            ePQ[l] = make_float2(sP0, sIp0);
            if (l < 28) { eGI[64+l] = make_float2(sI1,sII1); ePQ[64+l] = make_float2(sP1,sIp1); }
            LDS_WAIT();
            float SI=0,SII=0,SPx=0,SIp=0;
            #pragma unroll
            for (int d=0; d<15; ++d) {
                float2 u = eGI[l+d]; SI  += u.x; SII += u.y;
                float2 v = ePQ[l+d]; SPx += v.x; SIp += v.y;
            }
            float SI2=0,SII2=0,SP2=0,SIp2=0;
            if (l < 14) {
                #pragma unroll
                for (int d=0; d<15; ++d) {
                    float2 u = eGI[64+l+d]; SI2 += u.x; SII2 += u.y;
                    float2 v = ePQ[64+l+d]; SP2 += v.x; SIp2 += v.y;
                }
            }
            WAVE_FENCE();
            float mI = SI*inv225, mP = SPx*inv225;
            float a0 = (SIp*inv225 - mI*mP) / (SII*inv225 - mI*mI + 1e-3f);
            float b0 = mP - a0*mI;
            ring[t&15][l] = make_float2(a0,b0);
            sA0 += a0; sB0 += b0;
            if (l < 14) {
                float mI2 = SI2*inv225, mP2 = SP2*inv225;
                float a1 = (SIp2*inv225 - mI2*mP2) / (SII2*inv225 - mI2*mI2 + 1e-3f);
                float b1 = mP2 - a1*mI2;
                ring[t&15][64+l] = make_float2(a1,b1);
                sA1 += a1; sB1 += b1;
            }
        }
        // remove a,b row t-15 from the cascade col-sums (only rows actually produced)
        if (t >= y0+8 && t-15 >= 0) {
            float2 o0 = ring[(t-15)&15][l];
            sA0 -= o0.x; sB0 -= o0.y;
            if (l < 14) { float2 o1 = ring[(t-15)&15][64+l]; sA1 -= o1.x; sB1 -= o1.y; }
        }
        // 5. emit output row e = t-7
        if (emitNow) {
            eAB[l] = make_float2(sA0, sB0);
            if (l < 14) eAB[64+l] = make_float2(sA1, sB1);
            LDS_WAIT();
            float SA=0, SB=0;
            #pragma unroll
            for (int d=0; d<15; ++d) { float2 u = eAB[l+d]; SA += u.x; SB += u.y; }
            WAVE_FENCE();
            float dcr = SA*inv225*ge + SB*inv225;
            float f = (0.1f + dcr) * inv11;
            int e = t-7;
            size_t off = (size_t)e*WW + c0 + l;
            oPl[off]         = s0 - f*(1.0f - r0);
            oPl[off+PLANE]   = s1 - f*(1.0f - r1);
            oPl[off+2*PLANE] = s2 - f*(1.0f - r2);
        }
    }
}

extern "C" void kernel_launch(void* const* d_in, const int* in_sizes, int n_in,
                              void* d_out, int out_size, void* d_ws, size_t ws_size,
                              hipStream_t stream) {
    const float* smoky = (const float*)d_in[0];
    const float* rho   = (const float*)d_in[1];
    float* out = (float*)d_out;
    unsigned* gpbuf = (unsigned*)d_ws;    // packed bf16 (guide, p): BATCH*PLANE u32

    k1_guide_minpool<<<BATCH*64, 256, 0, stream>>>(smoky, gpbuf);
    k23<<<BATCH*128, 64, 0, stream>>>(gpbuf, smoky, rho, out);
}

// Round 7
// 85.116 us; speedup vs baseline: 1.5344x; 1.5344x over previous
//
#include <hip/hip_runtime.h>

#define BATCH 16
#define HH 512
#define WW 512
#define PLANE (HH*WW)

// Compiler memory-order fences for wave-synchronous LDS exchange.
#define LDS_WAIT()   asm volatile("s_waitcnt lgkmcnt(0)" ::: "memory")
#define WAVE_FENCE() asm volatile("" ::: "memory")

// bf16 pair helpers: word = x in low 16 bits, y in high 16 bits
__device__ __forceinline__ float bf_lo(unsigned u) {
    union { unsigned u; float f; } c; c.u = u << 16; return c.f;
}
__device__ __forceinline__ float bf_hi(unsigned u) {
    union { unsigned u; float f; } c; c.u = u & 0xFFFF0000u; return c.f;
}
__device__ __forceinline__ unsigned f2bf(float f) {   // RTNE, returns low-16 bf16
    union { float f; unsigned u; } c; c.f = f;
    return (c.u + 0x7FFFu + ((c.u >> 16) & 1u)) >> 16;
}
__device__ __forceinline__ unsigned packbf(float x, float y) {
    return f2bf(x) | (f2bf(y) << 16);
}

// ---------------- K1: guide (channel mean) + 15x15 replicate min-pool -> packed bf16 (g,p) ----------------
#define T1 64
#define HALO 7
#define LW (T1 + 2*HALO)   // 78

__global__ __launch_bounds__(256) void k1_guide_minpool(
    const float* __restrict__ smoky, unsigned* __restrict__ gp)
{
    __shared__ float dcp[LW*LW];          // per-pixel channel min, with replicate halo
    __shared__ float vmn[T1*LW];          // vertical 15-min
    __shared__ unsigned short gsh[T1*T1]; // guide (bf16) for interior
    int nwg = gridDim.x;             // 1024, divisible by 8
    int wg = (blockIdx.x & 7) * (nwg >> 3) + (blockIdx.x >> 3);  // XCD-chunked swizzle
    int img  = wg >> 6;              // 64 tiles per image
    int tile = wg & 63;
    int y0 = (tile >> 3) * T1;
    int x0 = (tile & 7) * T1;
    int t = threadIdx.x;
    const float* s0 = smoky + (size_t)img * 3 * PLANE;
    unsigned* gpl = gp + (size_t)img * PLANE;

    for (int i = t; i < LW*LW; i += 256) {
        int ly = i / LW, lx = i - ly * LW;
        int iy = y0 - HALO + ly, ix = x0 - HALO + lx;
        int cy = min(max(iy, 0), HH-1);
        int cx = min(max(ix, 0), WW-1);
        const float* bp = s0 + cy * WW + cx;
        float c0 = bp[0], c1 = bp[PLANE], c2 = bp[2*PLANE];
        dcp[i] = fminf(fminf(c0, c1), c2);
        if (ly >= HALO && ly < HALO+T1 && lx >= HALO && lx < HALO+T1)
            gsh[(ly-HALO)*T1 + (lx-HALO)] = (unsigned short)f2bf((c0 + c1 + c2) * (1.0f/3.0f));
    }
    __syncthreads();
    for (int i = t; i < T1*LW; i += 256) {
        int r = i / LW, c = i - r * LW;
        float m = dcp[r*LW + c];
        #pragma unroll
        for (int d = 1; d < 15; ++d) m = fminf(m, dcp[(r+d)*LW + c]);
        vmn[i] = m;
    }
    __syncthreads();
    for (int i = t; i < T1*T1; i += 256) {
        int r = i >> 6, c = i & 63;
        float m = vmn[r*LW + c];
        #pragma unroll
        for (int d = 1; d < 15; ++d) m = fminf(m, vmn[r*LW + c + d]);
        gpl[(y0+r)*WW + x0 + c] = (unsigned)gsh[r*T1+c] | (f2bf(m) << 16);
    }
}

// ---------------- K2: wave-autonomous fused box sums (I, I^2, p, I*p) -> packed bf16 (a,b) ----------------
#define RS2 16

__global__ __launch_bounds__(256) void k2_ab(
    const unsigned* __restrict__ gp, unsigned* __restrict__ abO)
{
    __shared__ float ls[4][4][80];   // [wave][quantity][slot]
    int nwg = gridDim.x;             // 1024
    int wg = (blockIdx.x & 7) * (nwg >> 3) + (blockIdx.x >> 3);
    int w = threadIdx.x >> 6, l = threadIdx.x & 63;
    int gw = wg * 4 + w;             // 0..4095
    int img   = gw >> 8;             // 256 waves per image
    int cg    = (gw >> 5) & 7;
    int strip = gw & 31;
    int y0 = strip * RS2;
    int c0 = cg * 64;
    const unsigned* gpP = gp + (size_t)img * PLANE;
    unsigned* abP = abO + (size_t)img * PLANE;

    // LDS slot s <-> global column c0-7+s
    int col0 = c0 - 7 + l;      // slot l
    int col1 = c0 + 57 + l;     // slot 64+l (lanes 0..13)
    bool v0 = (col0 >= 0);
    bool v1 = (l < 14) && (col1 < WW);

    float sI0=0,sII0=0,sP0=0,sIp0=0;
    float sI1=0,sII1=0,sP1=0,sIp1=0;

    auto loadrow = [&](int y, unsigned& u0, unsigned& u1) {
        u0 = 0u; u1 = 0u;
        if ((unsigned)y < (unsigned)HH) {
            const unsigned* r = gpP + (size_t)y * WW;
            if (v0) u0 = r[col0];
            if (v1) u1 = r[col1];
        }
    };

    // warm-up: window(y0-1) = rows y0-8 .. y0+6 (15 rows, zero outside)
    for (int r = y0 - 8; r <= y0 + 6; ++r) {
        unsigned u0,u1; loadrow(r, u0,u1);
        float g0=bf_lo(u0), p0=bf_hi(u0), g1=bf_lo(u1), p1=bf_hi(u1);
        sI0+=g0; sII0+=g0*g0; sP0+=p0; sIp0+=g0*p0;
        sI1+=g1; sII1+=g1*g1; sP1+=p1; sIp1+=g1*p1;
    }
    unsigned adA, adB, sbA, sbB;
    loadrow(y0 + 7, adA, adB);   // to add at iter y0
    loadrow(y0 - 8, sbA, sbB);   // to subtract at iter y0

    float* L = &ls[w][0][0];
    const float inv225 = 1.0f/225.0f;
    for (int y = y0; y < y0 + RS2; ++y) {
        // window(y) = window(y-1) + row(y+7) - row(y-8)
        {
            float gA0=bf_lo(adA), pA0=bf_hi(adA), gA1=bf_lo(adB), pA1=bf_hi(adB);
            float gS0=bf_lo(sbA), pS0=bf_hi(sbA), gS1=bf_lo(sbB), pS1=bf_hi(sbB);
            sI0 += gA0-gS0; sII0 += gA0*gA0-gS0*gS0; sP0 += pA0-pS0; sIp0 += gA0*pA0-gS0*pS0;
            sI1 += gA1-gS1; sII1 += gA1*gA1-gS1*gS1; sP1 += pA1-pS1; sIp1 += gA1*pA1-gS1*pS1;
        }
        // prefetch next iteration's rows (in flight during LDS phase)
        loadrow(y + 8, adA, adB);
        loadrow(y - 7, sbA, sbB);
        // wave-private LDS exchange (fenced wave-synchronous pattern)
        L[l] = sI0; L[80+l] = sII0; L[160+l] = sP0; L[240+l] = sIp0;
        if (l < 14) { L[64+l] = sI1; L[144+l] = sII1; L[224+l] = sP1; L[304+l] = sIp1; }
        LDS_WAIT();
        float SI=0,SII=0,SP=0,SIp=0;
        #pragma unroll
        for (int d = 0; d < 15; ++d) {
            SI  += L[l+d];
            SII += L[80+l+d];
            SP  += L[160+l+d];
            SIp += L[240+l+d];
        }
        WAVE_FENCE();   // keep next iter's ds_writes below this iter's ds_reads
        float mI = SI*inv225, mP = SP*inv225;
        float va = (SIp*inv225 - mI*mP) / (SII*inv225 - mI*mI + 1e-3f);
        abP[(size_t)y*WW + c0 + l] = packbf(va, mP - va*mI);
    }
}

// ---------------- K3: wave-autonomous box sums of bf16 (a,b) + guided output + combine ----------------
__global__ __launch_bounds__(256) void k3_final(
    const unsigned* __restrict__ abI, const unsigned* __restrict__ gp,
    const float* __restrict__ smoky, const float* __restrict__ rho,
    float* __restrict__ out)
{
    __shared__ float ls[4][2][80];
    int nwg = gridDim.x;             // 1024
    int wg = (blockIdx.x & 7) * (nwg >> 3) + (blockIdx.x >> 3);
    int w = threadIdx.x >> 6, l = threadIdx.x & 63;
    int gw = wg * 4 + w;
    int img   = gw >> 8;
    int cg    = (gw >> 5) & 7;
    int strip = gw & 31;
    int y0 = strip * RS2;
    int c0 = cg * 64;
    const unsigned* abP = abI + (size_t)img * PLANE;
    const unsigned* gpP = gp + (size_t)img * PLANE;
    const float* sP = smoky + (size_t)img * 3 * PLANE;
    const float* rP = rho   + (size_t)img * 3 * PLANE;
    float* oP = out + (size_t)img * 3 * PLANE;

    int col0 = c0 - 7 + l;
    int col1 = c0 + 57 + l;
    bool v0 = (col0 >= 0);
    bool v1 = (l < 14) && (col1 < WW);

    float sa0=0, sb0=0, sa1=0, sb1=0;

    auto loadrow = [&](int y, unsigned& u0, unsigned& u1) {
        u0 = 0u; u1 = 0u;
        if ((unsigned)y < (unsigned)HH) {
            const unsigned* r = abP + (size_t)y * WW;
            if (v0) u0 = r[col0];
            if (v1) u1 = r[col1];
        }
    };

    for (int r = y0 - 8; r <= y0 + 6; ++r) {
        unsigned u0,u1; loadrow(r, u0,u1);
        sa0 += bf_lo(u0); sb0 += bf_hi(u0);
        sa1 += bf_lo(u1); sb1 += bf_hi(u1);
    }
    unsigned adA, adB, sbA, sbB;
    loadrow(y0 + 7, adA, adB);
    loadrow(y0 - 8, sbA, sbB);

    // prefetched emit operands (guide/smoky/rho at current row)
    unsigned egu; float es0,es1,es2, er0,er1,er2;
    int yend = y0 + RS2;
    auto loademit = [&](int y) {
        if (y < yend) {
            size_t off = (size_t)y*WW + c0 + l;
            egu = gpP[off];
            es0 = sP[off]; es1 = sP[off+PLANE]; es2 = sP[off+2*PLANE];
            er0 = rP[off]; er1 = rP[off+PLANE]; er2 = rP[off+2*PLANE];
        }
    };
    loademit(y0);

    float* L = &ls[w][0][0];
    const float inv225 = 1.0f/225.0f;
    const float inv11  = 1.0f/1.1f;
    for (int y = y0; y < yend; ++y) {
        sa0 += bf_lo(adA) - bf_lo(sbA);  sb0 += bf_hi(adA) - bf_hi(sbA);
        sa1 += bf_lo(adB) - bf_lo(sbB);  sb1 += bf_hi(adB) - bf_hi(sbB);
        // consume current emit operands into locals
        float g = bf_lo(egu);
        float s0 = es0, s1 = es1, s2 = es2, r0 = er0, r1 = er1, r2 = er2;
        // prefetch next iteration
        loadrow(y + 8, adA, adB);
        loadrow(y - 7, sbA, sbB);
        loademit(y + 1);
        // wave-private LDS exchange (fenced wave-synchronous pattern)
        L[l] = sa0; L[80+l] = sb0;
        if (l < 14) { L[64+l] = sa1; L[144+l] = sb1; }
        LDS_WAIT();
        float SA=0, SB=0;
        #pragma unroll
        for (int d = 0; d < 15; ++d) { SA += L[l+d]; SB += L[80+l+d]; }
        WAVE_FENCE();
        float dcr = SA*inv225*g + SB*inv225;
        float f = (0.1f + dcr) * inv11;
        size_t off = (size_t)y*WW + c0 + l;
        oP[off]          = s0 - f*(1.0f - r0);
        oP[off+PLANE]    = s1 - f*(1.0f - r1);
        oP[off+2*PLANE]  = s2 - f*(1.0f - r2);
    }
}

extern "C" void kernel_launch(void* const* d_in, const int* in_sizes, int n_in,
                              void* d_out, int out_size, void* d_ws, size_t ws_size,
                              hipStream_t stream) {
    const float* smoky = (const float*)d_in[0];
    const float* rho   = (const float*)d_in[1];
    float* out = (float*)d_out;
    const size_t P = (size_t)BATCH * PLANE;
    unsigned* gpbuf = (unsigned*)d_ws;        // packed bf16 (guide,p): P u32
    unsigned* abbuf = (unsigned*)d_ws + P;    // packed bf16 (a,b): P u32

    k1_guide_minpool<<<BATCH*64, 256, 0, stream>>>(smoky, gpbuf);
    k2_ab<<<BATCH*64, 256, 0, stream>>>(gpbuf, abbuf);
    k3_final<<<BATCH*64, 256, 0, stream>>>(abbuf, gpbuf, smoky, rho, out);
}